// Round 13
// baseline (428.028 us; speedup 1.0000x reference)
//
#include <hip/hip_runtime.h>
#include <cstdint>
#include <cstddef>

// DiagonalLSTM B=32,C=64,H=64,W=64,h=64,4h=256,NW=127 — v18.
// v18 = v17 + scan LSTM full-rate math packed as float2 (v_pk_*_f32):
// cells processed in pairs; exp2/rcp remain scalar (no packed
// transcendentals); arithmetic bit-identical (same IEEE f32 ops).
// Also: deferred-store validity computed from (t-1-p2) directly
// (drops vstPrev/hpPrev carried state). K1 (3 nulled theories) and K3
// are parked — scan is the only kernel still being tuned.

typedef unsigned int u32;
typedef unsigned short u16;
typedef __bf16 bf16x8 __attribute__((ext_vector_type(8)));
typedef float f32x4 __attribute__((ext_vector_type(4)));
typedef float f32x2 __attribute__((ext_vector_type(2)));

#define NSTEP 127
#define MFMA(a, b, c) __builtin_amdgcn_mfma_f32_16x16x32_bf16(a, b, c, 0, 0, 0)
#define LOG2E 1.4426950408889634f
#define SCL (-1.4426950408889634f)
#define T2L 2.8853900817779268f
#define RHO(r) ((((r) ^ ((r) >> 3))) & 7)

static __device__ __forceinline__ u16 f2bf(float f) {
    u32 u = __builtin_bit_cast(u32, f);
    u32 r = u + 0x7FFFu + ((u >> 16) & 1u);
    return (u16)(r >> 16);
}
static __device__ __forceinline__ u32 cvt_pk_bf16(float a, float b) {
    // dst.lo = bf16(a), dst.hi = bf16(b); RNE — bit-identical to f2bf.
    u32 d;
    asm("v_cvt_pk_bf16_f32 %0, %1, %2" : "=v"(d) : "v"(a), "v"(b));
    return d;
}
static __device__ __forceinline__ float lo2f(u32 u) {
    return __builtin_bit_cast(float, u << 16);
}
static __device__ __forceinline__ float hi2f(u32 u) {
    return __builtin_bit_cast(float, u & 0xFFFF0000u);
}

// ---------------- K0: weight repack ----------------
__global__ __launch_bounds__(256) void repack_w(
    const float* __restrict__ w_s2s, const float* __restrict__ w_c2c,
    const float* __restrict__ bi, const float* __restrict__ bs,
    const float* __restrict__ w_up, float* __restrict__ Wg,
    float* __restrict__ Wc, u16* __restrict__ biasRow,
    u16* __restrict__ w_upB) {
    int idx = blockIdx.x * 256 + threadIdx.x;
    if (idx < 32768) {
        int o = idx >> 7, kk = idx & 127, half = kk >> 6, k = kk & 63;
        Wg[idx] = SCL * w_s2s[(o * 64 + k) * 2 + half];
        return;
    }
    int j = idx - 32768;
    if (j < 8192) {
        int o = j >> 7, kk = j & 127, half = kk >> 6, k = kk & 63;
        Wc[j] = w_c2c[(o * 64 + k) * 2 + half];
        return;
    }
    j -= 8192;
    if (j < 256) {
        int m15 = j >> 4, nq = (j >> 2) & 3, nb = j & 3;
        int o = 64 * nq + 16 * nb + m15;
        biasRow[j] = f2bf(SCL * (bi[o] + bs[o]));
        return;
    }
    j -= 256;
    if (j < 8192) w_upB[j] = f2bf(w_up[j]);
}

// ---------------- K1: i2s conv via MFMA (LDS union: Xt aliases sT) --------
__global__ __launch_bounds__(256, 4) void i2s_kernel(
    const float* __restrict__ in, const float* __restrict__ w_i2s,
    const float* __restrict__ bi, const float* __restrict__ bs,
    const u32* __restrict__ biasU32, u32* __restrict__ out_u32) {
    const int bid = blockIdx.x;
    const int b = bid >> 6, r = bid & 63;
    const int tid = threadIdx.x;
    const int lane = tid & 63;
    const int wv = __builtin_amdgcn_readfirstlane(tid >> 6);
    const int m15 = lane & 15, g4 = lane >> 4;

    __shared__ __align__(16) u32 sT[64 * 129];  // 33024 B -> 4 blocks/CU
    char* XtB = (char*)sT;

    {
        const int w = tid & 63, cp = tid >> 6;
        const float* xp = in + (size_t)b * 262144 + r * 64 + w;
#pragma unroll
        for (int pass = 0; pass < 8; pass++) {
            int c = pass * 8 + cp * 2;
            float x0 = xp[(size_t)c * 4096];
            float x1 = xp[(size_t)(c + 1) * 4096];
            *(u32*)(XtB + ((w * 128 + c * 2) ^ ((w & 7) << 4))) =
                cvt_pk_bf16(x0, x1);
        }
    }

    bf16x8 Af[4][2];
#pragma unroll
    for (int m = 0; m < 4; m++)
#pragma unroll
        for (int kt = 0; kt < 2; kt++) {
            const float4* p = (const float4*)(w_i2s +
                                              (wv * 64 + m * 16 + m15) * 64 +
                                              kt * 32 + g4 * 8);
            float4 a = p[0], bq = p[1];
            uint4 u;
            u.x = cvt_pk_bf16(a.x, a.y);
            u.y = cvt_pk_bf16(a.z, a.w);
            u.z = cvt_pk_bf16(bq.x, bq.y);
            u.w = cvt_pk_bf16(bq.z, bq.w);
            Af[m][kt] = __builtin_bit_cast(bf16x8, u);
        }
    float bias[4][4];
#pragma unroll
    for (int m = 0; m < 4; m++) {
        int o = wv * 64 + m * 16 + 4 * g4;
        float4 vb = *(const float4*)(bi + o);
        float4 vs = *(const float4*)(bs + o);
        bias[m][0] = vb.x + vs.x;
        bias[m][1] = vb.y + vs.y;
        bias[m][2] = vb.z + vs.z;
        bias[m][3] = vb.w + vs.w;
    }

    __syncthreads();

    f32x4 acc[4][4] = {};
#pragma unroll
    for (int nt = 0; nt < 4; nt++) {
        const int w = nt * 16 + m15;
        bf16x8 Bf[2];
#pragma unroll
        for (int kt = 0; kt < 2; kt++)
            Bf[kt] = __builtin_bit_cast(
                bf16x8, *(const uint4*)(XtB + ((w * 128 + kt * 64 + g4 * 16) ^
                                               ((w & 7) << 4))));
#pragma unroll
        for (int m = 0; m < 4; m++)
#pragma unroll
            for (int kt = 0; kt < 2; kt++)
                acc[m][nt] = MFMA(Af[m][kt], Bf[kt], acc[m][nt]);
    }

    __syncthreads();  // all Xt reads complete before sT overwrites its bytes

#pragma unroll
    for (int nt = 0; nt < 4; nt++) {
        const int w = nt * 16 + m15;
#pragma unroll
        for (int reg = 0; reg < 4; reg++)
#pragma unroll
            for (int mp = 0; mp < 2; mp++) {
                float v0 = SCL * (acc[2 * mp][nt][reg] + bias[2 * mp][reg]);
                float v1 =
                    SCL * (acc[2 * mp + 1][nt][reg] + bias[2 * mp + 1][reg]);
                sT[w * 129 + (4 * g4 + reg) * 8 + wv * 2 + mp] =
                    cvt_pk_bf16(v0, v1);
            }
    }
    __syncthreads();

    const size_t base = ((size_t)(b * 64 + r) * 66 + 1) * 128;
#pragma unroll
    for (int loop = 0; loop < 32; loop++) {
        int idx = loop * 256 + tid;
        int w = idx >> 7, cu = idx & 127;
        out_u32[base + idx] = sT[w * 129 + cu];
    }
    if (tid < 128) {
        u32 v = biasU32[tid];
        out_u32[base - 128 + tid] = v;
        out_u32[base + 8192 + tid] = v;
    }
}

// ---------------- K2: MFMA scan v18 ----------------
// 32 blocks x 512 threads (8 waves). LDS sM bytes: [0,8192) H par0;
// [8192,16384) H par1; [16384,32768) C par0/par1; ZH0@32768 ZC0@32896
// ZH1@40960 ZC1@41088. All addrs XOR 8192 per step; RHO chunk swizzle.
// v14 structure; v18: float2-packed LSTM full-rate math, stateless
// deferred-store validity.
__global__ __launch_bounds__(512, 2) void scan_kernel(
    const u16* __restrict__ i2sP, const float* __restrict__ Wg,
    const float* __restrict__ Wc, const float* __restrict__ b_c2c,
    u16* __restrict__ hh16) {
    const int b = blockIdx.x;
    const int tid = threadIdx.x;
    const int lane = tid & 63;
    const int wv = __builtin_amdgcn_readfirstlane(tid >> 6);
    const int mh = wv >> 2, nq = wv & 3;
    const int m15 = lane & 15, g4 = lane >> 4;

    __shared__ __align__(16) u32 sM[10304];  // 41216 B
    char* smB = (char*)sM;

    for (int i = tid; i < 10304; i += 512) sM[i] = 0;

    // ---- VGPR-resident weights ----
    bf16x8 BW[4][4];
    float bcc[4];
#pragma unroll
    for (int nb = 0; nb < 4; nb++) {
        int o = 64 * nq + 16 * nb + m15;
        bcc[nb] = b_c2c[16 * nb + m15];
#pragma unroll
        for (int kt = 0; kt < 4; kt++) {
            const float* p = Wg + o * 128 + kt * 32 + g4 * 8;
            bf16x8 f;
#pragma unroll
            for (int j = 0; j < 8; j++) f[j] = (__bf16)p[j];
            BW[nb][kt] = f;
        }
    }
    bf16x8 BC[4][4];  // all 4 chan-tiles
#pragma unroll
    for (int nb = 0; nb < 4; nb++) {
        int o2 = 16 * nb + m15;
#pragma unroll
        for (int kt = 0; kt < 4; kt++) {
            const float* p = Wc + o2 * 128 + kt * 32 + g4 * 8;
            bf16x8 f;
#pragma unroll
            for (int j = 0; j < 8; j++) f[j] = (__bf16)p[j];
            BC[nb][kt] = f;
        }
    }

    // ---- precomputed addresses ----
    int aG[2][4], aC[4], wOff[2][4];
    u32 offW[2][4], offLo[2][4], offHi[2][4];
#pragma unroll
    for (int mi = 0; mi < 2; mi++) {
        int mt = 2 * mh + mi;
#pragma unroll
        for (int kt = 0; kt < 4; kt++) {
            int P = 16 * (m15 & 3) + 4 * mt + (m15 >> 2);
            int phys = P + (kt >> 1) - 1;
            int chunk = (kt & 1) * 4 + g4;
            aG[mi][kt] = (phys < 0) ? (32768 + chunk * 16)
                                    : (phys * 128 + ((chunk ^ RHO(phys)) * 16));
        }
        int p2 = 16 * mt + 4 * g4 + nq;
#pragma unroll
        for (int nb = 0; nb < 4; nb++) {
            int k = 16 * nb + m15;
            wOff[mi][nb] =
                8192 + p2 * 128 + (((k >> 3) ^ RHO(p2)) * 16) + (k & 7) * 2;
            int prerow = 16 * nb + 4 * mt + g4;  // nb doubles as gate idx r
            int bOffB = (prerow * 66 + 1) * 512 + 32 * m15 + 8 * nq;
            // walked u32 offset for the t+1 prefetch (clamped to w in [-1,64])
            offW[mi][nb] = (u32)(bOffB + ((1 - prerow) << 9));
            offLo[mi][nb] = (u32)(bOffB - 512);
            offHi[mi][nb] = (u32)(bOffB + 32768);
        }
    }
    // c2c: ROW-INTERLEAVED tile — even tile-rows = mt0, odd = mt1:
    //   crow(m15) = 16*(2mh + (m15&1)) + (m15&12) + nq
    // reg0 -> mi=0 row (16*mt0 + 4g4 + nq), reg1 -> mi=1 row.
#pragma unroll
    for (int kt = 0; kt < 4; kt++) {
        int crow = 16 * (2 * mh + (m15 & 1)) + (m15 & 12) + nq;
        int cphys = crow + (kt >> 1) - 1;
        int chunk = (kt & 1) * 4 + g4;
        aC[kt] = (cphys < 0)
                     ? (32896 + chunk * 16)
                     : (16384 + cphys * 128 + ((chunk ^ RHO(cphys)) * 16));
    }

    const char* i2sB = (const char*)i2sP + (size_t)b * (64 * 66 * 512);
    u16* hp16[2];
    int p2s[2];
#pragma unroll
    for (int mi = 0; mi < 2; mi++) {
        int p2 = 16 * (2 * mh + mi) + 4 * g4 + nq;
        p2s[mi] = p2;
        hp16[mi] = hh16 + (size_t)b * 262144 + p2 * 4032 + m15;
    }

    // ---- initial IV load (t=0) ----
    uint2 IV[2][4];
#pragma unroll
    for (int mi = 0; mi < 2; mi++) {
#pragma unroll
        for (int r = 0; r < 4; r++) {
            u32 o0 = min(max(offW[mi][r] - 512u, offLo[mi][r]), offHi[mi][r]);
            IV[mi][r] = *(const uint2*)(i2sB + o0);
        }
    }

    u16 hbKeep[2][4];  // h values of step t-1, stored at top of step t

    __syncthreads();

    for (int t = 0; t < NSTEP; t++) {
        // ---- deferred hh16 stores from step t-1 (validity stateless) ----
#pragma unroll
        for (int mi = 0; mi < 2; mi++)
            if ((u32)(t - 1 - p2s[mi]) < 64u) {
                u16* hp = hp16[mi] - 64;
#pragma unroll
                for (int nb = 0; nb < 4; nb++)
                    hp[nb * 16] = hbKeep[mi][nb];
            }

        // ---- c2c ONCE per step (row-interleaved tile serves both mi) ----
        f32x4 accC[4];
#pragma unroll
        for (int nb = 0; nb < 4; nb++) {
            accC[nb][0] = bcc[nb];
            accC[nb][1] = bcc[nb];
            accC[nb][2] = bcc[nb];
            accC[nb][3] = bcc[nb];
        }
        {
            bf16x8 Ac[4];
#pragma unroll
            for (int kt = 0; kt < 4; kt++)
                Ac[kt] = __builtin_bit_cast(bf16x8,
                                            *(const uint4*)(smB + aC[kt]));
#pragma unroll
            for (int nb = 0; nb < 4; nb++)
#pragma unroll
                for (int kt = 0; kt < 4; kt++)
                    accC[nb] = MFMA(Ac[kt], BC[nb][kt], accC[nb]);
        }

        // ---- per-mi: prefetch | acc-init+gates | LSTM+writes ----
#pragma unroll
        for (int mi = 0; mi < 2; mi++) {
            // prefetch IV for step t+1 (walked offsets, clamped)
            uint2 tn[4];
#pragma unroll
            for (int r = 0; r < 4; r++) {
                u32 oc = min(max(offW[mi][r], offLo[mi][r]), offHi[mi][r]);
                tn[r] = *(const uint2*)(i2sB + oc);
            }

            // gate MFMAs, acc initialized from current IV
            f32x4 accG[4];
#pragma unroll
            for (int r = 0; r < 4; r++) {
                accG[0][r] = lo2f(IV[mi][r].x);
                accG[1][r] = hi2f(IV[mi][r].x);
                accG[2][r] = lo2f(IV[mi][r].y);
                accG[3][r] = hi2f(IV[mi][r].y);
            }
            bf16x8 Ag[4];
#pragma unroll
            for (int kt = 0; kt < 4; kt++)
                Ag[kt] = __builtin_bit_cast(bf16x8,
                                            *(const uint4*)(smB + aG[mi][kt]));
#pragma unroll
            for (int nb = 0; nb < 4; nb++)
#pragma unroll
                for (int kt = 0; kt < 4; kt++)
                    accG[nb] = MFMA(Ag[kt], BW[nb][kt], accG[nb]);

            // LSTM update, rcp-fused, cell-pair packed (v_pk_*_f32):
            //   pX = 1+exp2(yX); c1 = (cc*u + pF) / (pF*u), u = pI*pG
            //   E = exp2(c1*T2L); h1 = (E-1) / ((1+E)*pO)
#pragma unroll
            for (int np = 0; np < 2; np++) {
                const int n0 = 2 * np, n1 = n0 + 1;
                f32x2 pI = {__builtin_amdgcn_exp2f(accG[n0][0]),
                            __builtin_amdgcn_exp2f(accG[n1][0])};
                f32x2 pG = {__builtin_amdgcn_exp2f(accG[n0][1]),
                            __builtin_amdgcn_exp2f(accG[n1][1])};
                f32x2 pF = {__builtin_amdgcn_exp2f(accG[n0][2]),
                            __builtin_amdgcn_exp2f(accG[n1][2])};
                f32x2 pO = {__builtin_amdgcn_exp2f(accG[n0][3]),
                            __builtin_amdgcn_exp2f(accG[n1][3])};
                pI = pI + 1.f;
                pG = pG + 1.f;
                pF = pF + 1.f;
                pO = pO + 1.f;
                f32x2 cc = {accC[n0][mi], accC[n1][mi]};
                f32x2 u = pI * pG;
                f32x2 num = cc * u + pF;  // v_pk_fma_f32
                f32x2 den = pF * u;
                f32x2 rd = {__builtin_amdgcn_rcpf(den[0]),
                            __builtin_amdgcn_rcpf(den[1])};
                f32x2 c1 = num * rd;
                f32x2 ar = c1 * T2L;
                f32x2 E = {__builtin_amdgcn_exp2f(ar[0]),
                           __builtin_amdgcn_exp2f(ar[1])};
                f32x2 t1 = (E + 1.f) * pO;
                f32x2 rt = {__builtin_amdgcn_rcpf(t1[0]),
                            __builtin_amdgcn_rcpf(t1[1])};
                f32x2 h1 = (E - 1.f) * rt;
                u32 hc0 = cvt_pk_bf16(h1[0], c1[0]);
                u32 hc1 = cvt_pk_bf16(h1[1], c1[1]);
                *(u16*)(smB + wOff[mi][n0]) = (u16)hc0;
                *(u16*)(smB + wOff[mi][n0] + 16384) = (u16)(hc0 >> 16);
                *(u16*)(smB + wOff[mi][n1]) = (u16)hc1;
                *(u16*)(smB + wOff[mi][n1] + 16384) = (u16)(hc1 >> 16);
                hbKeep[mi][n0] = (u16)hc0;
                hbKeep[mi][n1] = (u16)hc1;
            }
            hp16[mi] += 64;

            // rotate prefetched IV
#pragma unroll
            for (int r = 0; r < 4; r++) IV[mi][r] = tn[r];
        }

        __syncthreads();  // single barrier per step

        // ---- toggle parity; walk IV offsets ----
#pragma unroll
        for (int kt = 0; kt < 4; kt++) aC[kt] ^= 8192;
#pragma unroll
        for (int mi = 0; mi < 2; mi++) {
#pragma unroll
            for (int kt = 0; kt < 4; kt++) aG[mi][kt] ^= 8192;
#pragma unroll
            for (int nb = 0; nb < 4; nb++) {
                wOff[mi][nb] ^= 8192;
                offW[mi][nb] += 512;
            }
        }
    }

    // ---- epilogue: final deferred stores (step NSTEP-1) ----
#pragma unroll
    for (int mi = 0; mi < 2; mi++)
        if ((u32)(NSTEP - 1 - p2s[mi]) < 64u) {
            u16* hp = hp16[mi] - 64;
#pragma unroll
            for (int nb = 0; nb < 4; nb++)
                hp[nb * 16] = hbKeep[mi][nb];
        }
}

// ---------------- K3: up-projection via MFMA (unchanged) ----------
__global__ __launch_bounds__(256, 4) void up_kernel(
    const u16* __restrict__ hh16, const u16* __restrict__ w_upB,
    const float* __restrict__ b_up, float* __restrict__ out) {
    const int bid = blockIdx.x;
    const int b = bid >> 6, r = bid & 63;
    const int lane = threadIdx.x & 63;
    const int wt = __builtin_amdgcn_readfirstlane(threadIdx.x >> 6);
    const int m15 = lane & 15, g4 = lane >> 4;

    const u16* hh_b = hh16 + (size_t)b * 262144;
    const int w = 16 * wt + m15;

    bf16x8 Bf[2];
#pragma unroll
    for (int kt = 0; kt < 2; kt++)
        Bf[kt] = __builtin_bit_cast(
            bf16x8,
            *(const uint4*)(hh_b + (r * 4096 + w * 64 + kt * 32 + g4 * 8)));

    f32x4 bup[8];
#pragma unroll
    for (int nt = 0; nt < 8; nt++)
        bup[nt] =
            __builtin_bit_cast(f32x4, *(const float4*)(b_up + 16 * nt + 4 * g4));

    f32x4 acc[8] = {};
#pragma unroll
    for (int nt = 0; nt < 8; nt++) {
#pragma unroll
        for (int kt = 0; kt < 2; kt++) {
            bf16x8 Af = __builtin_bit_cast(
                bf16x8, *(const uint4*)(w_upB + ((16 * nt + m15) * 64 +
                                                 kt * 32 + g4 * 8)));
            acc[nt] = MFMA(Af, Bf[kt], acc[nt]);
        }
    }
    float* outb = out + (size_t)b * 524288;
#pragma unroll
    for (int nt = 0; nt < 8; nt++) {
#pragma unroll
        for (int rr = 0; rr < 4; rr++) {
            int o2 = 16 * nt + 4 * g4 + rr;
            outb[(size_t)o2 * 4096 + r * 64 + w] = acc[nt][rr] + bup[nt][rr];
        }
    }
}

extern "C" void kernel_launch(void* const* d_in, const int* in_sizes, int n_in,
                              void* d_out, int out_size, void* d_ws,
                              size_t ws_size, hipStream_t stream) {
    (void)in_sizes; (void)n_in; (void)out_size; (void)ws_size;
    const float* inputs = (const float*)d_in[0];
    const float* w_i2s = (const float*)d_in[1];
    const float* b_i2s = (const float*)d_in[2];
    const float* w_s2s = (const float*)d_in[3];
    const float* b_s2s = (const float*)d_in[4];
    const float* w_c2c = (const float*)d_in[5];
    const float* b_c2c = (const float*)d_in[6];
    const float* w_up = (const float*)d_in[7];
    const float* b_up = (const float*)d_in[8];
    float* out = (float*)d_out;
    char* ws = (char*)d_ws;

    // workspace layout (bytes):
    // [0, 69206016)             i2sP u16 (32*64*66*256, bias-padded slots)
    // [69206016, 85983232)      hh16 u16 (32*64*64*64)
    // [85983232, 86114304)      Wg fp32 (256*128, scaled -log2e)
    // [86114304, 86147072)      Wc fp32 (64*128)
    // [86147072, 86147584)      biasRow u16[256]
    // [86147584, 86163968)      w_upB u16 (128*64)
    u16* i2sP = (u16*)ws;
    u16* hh16 = (u16*)(ws + 69206016);
    float* Wg = (float*)(ws + 85983232);
    float* Wc = (float*)(ws + 86114304);
    u16* biasRow = (u16*)(ws + 86147072);
    u16* w_upB = (u16*)(ws + 86147584);

    hipLaunchKernelGGL(repack_w, dim3(193), dim3(256), 0, stream, w_s2s, w_c2c,
                       b_i2s, b_s2s, w_up, Wg, Wc, biasRow, w_upB);
    hipLaunchKernelGGL(i2s_kernel, dim3(2048), dim3(256), 0, stream, inputs,
                       w_i2s, b_i2s, b_s2s, (const u32*)biasRow, (u32*)i2sP);
    hipLaunchKernelGGL(scan_kernel, dim3(32), dim3(512), 0, stream, i2sP, Wg,
                       Wc, b_c2c, hh16);
    hipLaunchKernelGGL(up_kernel, dim3(2048), dim3(256), 0, stream, hh16,
                       w_upB, b_up, out);
}

// Round 14
// 402.943 us; speedup vs baseline: 1.0623x; 1.0623x over previous
//
#include <hip/hip_runtime.h>
#include <cstdint>
#include <cstddef>

// DiagonalLSTM B=32,C=64,H=64,W=64,h=64,4h=256,NW=127 — v19 = v17 (revert).
// v18's float2-packed LSTM REGRESSED (scan 265->289us): packing halved the
// number of independent dep-chains (8 scalar cells -> 4 pairs) and added
// vector build/extract movs around the scalar exp2/rcp — the VALU was
// dependency-limited, not throughput-limited, so ILP > packing. This file
// is the byte-exact v17: scalar rcp-fused LSTM, row-interleaved shared c2c,
// one barrier/step, deferred hh16 stores, IV prefetch->acc init, cvt_pk,
// K1 LDS-union (4 blocks/CU), vectorized K1/K3 param loads.
// Known-good measurement: total 400.1us, scan 264.7us steady.

typedef unsigned int u32;
typedef unsigned short u16;
typedef __bf16 bf16x8 __attribute__((ext_vector_type(8)));
typedef float f32x4 __attribute__((ext_vector_type(4)));

#define NSTEP 127
#define MFMA(a, b, c) __builtin_amdgcn_mfma_f32_16x16x32_bf16(a, b, c, 0, 0, 0)
#define LOG2E 1.4426950408889634f
#define SCL (-1.4426950408889634f)
#define T2L 2.8853900817779268f
#define RHO(r) ((((r) ^ ((r) >> 3))) & 7)

static __device__ __forceinline__ u16 f2bf(float f) {
    u32 u = __builtin_bit_cast(u32, f);
    u32 r = u + 0x7FFFu + ((u >> 16) & 1u);
    return (u16)(r >> 16);
}
static __device__ __forceinline__ u32 cvt_pk_bf16(float a, float b) {
    // dst.lo = bf16(a), dst.hi = bf16(b); RNE — bit-identical to f2bf.
    u32 d;
    asm("v_cvt_pk_bf16_f32 %0, %1, %2" : "=v"(d) : "v"(a), "v"(b));
    return d;
}
static __device__ __forceinline__ float lo2f(u32 u) {
    return __builtin_bit_cast(float, u << 16);
}
static __device__ __forceinline__ float hi2f(u32 u) {
    return __builtin_bit_cast(float, u & 0xFFFF0000u);
}

// ---------------- K0: weight repack ----------------
__global__ __launch_bounds__(256) void repack_w(
    const float* __restrict__ w_s2s, const float* __restrict__ w_c2c,
    const float* __restrict__ bi, const float* __restrict__ bs,
    const float* __restrict__ w_up, float* __restrict__ Wg,
    float* __restrict__ Wc, u16* __restrict__ biasRow,
    u16* __restrict__ w_upB) {
    int idx = blockIdx.x * 256 + threadIdx.x;
    if (idx < 32768) {
        int o = idx >> 7, kk = idx & 127, half = kk >> 6, k = kk & 63;
        Wg[idx] = SCL * w_s2s[(o * 64 + k) * 2 + half];
        return;
    }
    int j = idx - 32768;
    if (j < 8192) {
        int o = j >> 7, kk = j & 127, half = kk >> 6, k = kk & 63;
        Wc[j] = w_c2c[(o * 64 + k) * 2 + half];
        return;
    }
    j -= 8192;
    if (j < 256) {
        int m15 = j >> 4, nq = (j >> 2) & 3, nb = j & 3;
        int o = 64 * nq + 16 * nb + m15;
        biasRow[j] = f2bf(SCL * (bi[o] + bs[o]));
        return;
    }
    j -= 256;
    if (j < 8192) w_upB[j] = f2bf(w_up[j]);
}

// ---------------- K1: i2s conv via MFMA (LDS union: Xt aliases sT) --------
__global__ __launch_bounds__(256, 4) void i2s_kernel(
    const float* __restrict__ in, const float* __restrict__ w_i2s,
    const float* __restrict__ bi, const float* __restrict__ bs,
    const u32* __restrict__ biasU32, u32* __restrict__ out_u32) {
    const int bid = blockIdx.x;
    const int b = bid >> 6, r = bid & 63;
    const int tid = threadIdx.x;
    const int lane = tid & 63;
    const int wv = __builtin_amdgcn_readfirstlane(tid >> 6);
    const int m15 = lane & 15, g4 = lane >> 4;

    // Union: first 8192 B double as Xt (bf16 [w 64][c 64], swizzled) during
    // staging+MFMA; whole buffer is sT (u16 [w 64][o'' 256], u32 stride 129)
    // during the epilogue. Barrier between the two phases.
    __shared__ __align__(16) u32 sT[64 * 129];  // 33024 B -> 4 blocks/CU
    char* XtB = (char*)sT;

    {
        const int w = tid & 63, cp = tid >> 6;
        const float* xp = in + (size_t)b * 262144 + r * 64 + w;
#pragma unroll
        for (int pass = 0; pass < 8; pass++) {
            int c = pass * 8 + cp * 2;
            float x0 = xp[(size_t)c * 4096];
            float x1 = xp[(size_t)(c + 1) * 4096];
            *(u32*)(XtB + ((w * 128 + c * 2) ^ ((w & 7) << 4))) =
                cvt_pk_bf16(x0, x1);
        }
    }

    // A fragments: 2x float4 + 4x cvt_pk per frag
    bf16x8 Af[4][2];
#pragma unroll
    for (int m = 0; m < 4; m++)
#pragma unroll
        for (int kt = 0; kt < 2; kt++) {
            const float4* p = (const float4*)(w_i2s +
                                              (wv * 64 + m * 16 + m15) * 64 +
                                              kt * 32 + g4 * 8);
            float4 a = p[0], bq = p[1];
            uint4 u;
            u.x = cvt_pk_bf16(a.x, a.y);
            u.y = cvt_pk_bf16(a.z, a.w);
            u.z = cvt_pk_bf16(bq.x, bq.y);
            u.w = cvt_pk_bf16(bq.z, bq.w);
            Af[m][kt] = __builtin_bit_cast(bf16x8, u);
        }
    // bias via float4 (o = wv*64 + m*16 + 4g4 + rr, rr 0..3 contiguous)
    float bias[4][4];
#pragma unroll
    for (int m = 0; m < 4; m++) {
        int o = wv * 64 + m * 16 + 4 * g4;
        float4 vb = *(const float4*)(bi + o);
        float4 vs = *(const float4*)(bs + o);
        bias[m][0] = vb.x + vs.x;
        bias[m][1] = vb.y + vs.y;
        bias[m][2] = vb.z + vs.z;
        bias[m][3] = vb.w + vs.w;
    }

    __syncthreads();

    f32x4 acc[4][4] = {};
#pragma unroll
    for (int nt = 0; nt < 4; nt++) {
        const int w = nt * 16 + m15;
        bf16x8 Bf[2];
#pragma unroll
        for (int kt = 0; kt < 2; kt++)
            Bf[kt] = __builtin_bit_cast(
                bf16x8, *(const uint4*)(XtB + ((w * 128 + kt * 64 + g4 * 16) ^
                                               ((w & 7) << 4))));
#pragma unroll
        for (int m = 0; m < 4; m++)
#pragma unroll
            for (int kt = 0; kt < 2; kt++)
                acc[m][nt] = MFMA(Af[m][kt], Bf[kt], acc[m][nt]);
    }

    __syncthreads();  // all Xt reads complete before sT overwrites its bytes

#pragma unroll
    for (int nt = 0; nt < 4; nt++) {
        const int w = nt * 16 + m15;
#pragma unroll
        for (int reg = 0; reg < 4; reg++)
#pragma unroll
            for (int mp = 0; mp < 2; mp++) {
                float v0 = SCL * (acc[2 * mp][nt][reg] + bias[2 * mp][reg]);
                float v1 =
                    SCL * (acc[2 * mp + 1][nt][reg] + bias[2 * mp + 1][reg]);
                sT[w * 129 + (4 * g4 + reg) * 8 + wv * 2 + mp] =
                    cvt_pk_bf16(v0, v1);
            }
    }
    __syncthreads();

    const size_t base = ((size_t)(b * 64 + r) * 66 + 1) * 128;
#pragma unroll
    for (int loop = 0; loop < 32; loop++) {
        int idx = loop * 256 + tid;
        int w = idx >> 7, cu = idx & 127;
        out_u32[base + idx] = sT[w * 129 + cu];
    }
    if (tid < 128) {
        u32 v = biasU32[tid];
        out_u32[base - 128 + tid] = v;
        out_u32[base + 8192 + tid] = v;
    }
}

// ---------------- K2: MFMA scan (v14 structure, known-good) ----------------
// 32 blocks x 512 threads (8 waves). LDS sM bytes: [0,8192) H par0;
// [8192,16384) H par1; [16384,32768) C par0/par1; ZH0@32768 ZC0@32896
// ZH1@40960 ZC1@41088. All addrs XOR 8192 per step; RHO chunk swizzle.
__global__ __launch_bounds__(512, 2) void scan_kernel(
    const u16* __restrict__ i2sP, const float* __restrict__ Wg,
    const float* __restrict__ Wc, const float* __restrict__ b_c2c,
    u16* __restrict__ hh16) {
    const int b = blockIdx.x;
    const int tid = threadIdx.x;
    const int lane = tid & 63;
    const int wv = __builtin_amdgcn_readfirstlane(tid >> 6);
    const int mh = wv >> 2, nq = wv & 3;
    const int m15 = lane & 15, g4 = lane >> 4;

    __shared__ __align__(16) u32 sM[10304];  // 41216 B
    char* smB = (char*)sM;

    for (int i = tid; i < 10304; i += 512) sM[i] = 0;

    // ---- VGPR-resident weights ----
    bf16x8 BW[4][4];
    float bcc[4];
#pragma unroll
    for (int nb = 0; nb < 4; nb++) {
        int o = 64 * nq + 16 * nb + m15;
        bcc[nb] = b_c2c[16 * nb + m15];
#pragma unroll
        for (int kt = 0; kt < 4; kt++) {
            const float* p = Wg + o * 128 + kt * 32 + g4 * 8;
            bf16x8 f;
#pragma unroll
            for (int j = 0; j < 8; j++) f[j] = (__bf16)p[j];
            BW[nb][kt] = f;
        }
    }
    bf16x8 BC[4][4];  // all 4 chan-tiles
#pragma unroll
    for (int nb = 0; nb < 4; nb++) {
        int o2 = 16 * nb + m15;
#pragma unroll
        for (int kt = 0; kt < 4; kt++) {
            const float* p = Wc + o2 * 128 + kt * 32 + g4 * 8;
            bf16x8 f;
#pragma unroll
            for (int j = 0; j < 8; j++) f[j] = (__bf16)p[j];
            BC[nb][kt] = f;
        }
    }

    // ---- precomputed addresses ----
    int aG[2][4], aC[4], wOff[2][4];
    u32 offW[2][4], offLo[2][4], offHi[2][4];
#pragma unroll
    for (int mi = 0; mi < 2; mi++) {
        int mt = 2 * mh + mi;
#pragma unroll
        for (int kt = 0; kt < 4; kt++) {
            int P = 16 * (m15 & 3) + 4 * mt + (m15 >> 2);
            int phys = P + (kt >> 1) - 1;
            int chunk = (kt & 1) * 4 + g4;
            aG[mi][kt] = (phys < 0) ? (32768 + chunk * 16)
                                    : (phys * 128 + ((chunk ^ RHO(phys)) * 16));
        }
        int p2 = 16 * mt + 4 * g4 + nq;
#pragma unroll
        for (int nb = 0; nb < 4; nb++) {
            int k = 16 * nb + m15;
            wOff[mi][nb] =
                8192 + p2 * 128 + (((k >> 3) ^ RHO(p2)) * 16) + (k & 7) * 2;
            int prerow = 16 * nb + 4 * mt + g4;  // nb doubles as gate idx r
            int bOffB = (prerow * 66 + 1) * 512 + 32 * m15 + 8 * nq;
            // walked u32 offset for the t+1 prefetch (clamped to w in [-1,64])
            offW[mi][nb] = (u32)(bOffB + ((1 - prerow) << 9));
            offLo[mi][nb] = (u32)(bOffB - 512);
            offHi[mi][nb] = (u32)(bOffB + 32768);
        }
    }
    // c2c: ROW-INTERLEAVED tile — even tile-rows = mt0, odd = mt1:
    //   crow(m15) = 16*(2mh + (m15&1)) + (m15&12) + nq
    // reg0 -> mi=0 row (16*mt0 + 4g4 + nq), reg1 -> mi=1 row.
#pragma unroll
    for (int kt = 0; kt < 4; kt++) {
        int crow = 16 * (2 * mh + (m15 & 1)) + (m15 & 12) + nq;
        int cphys = crow + (kt >> 1) - 1;
        int chunk = (kt & 1) * 4 + g4;
        aC[kt] = (cphys < 0)
                     ? (32896 + chunk * 16)
                     : (16384 + cphys * 128 + ((chunk ^ RHO(cphys)) * 16));
    }

    const char* i2sB = (const char*)i2sP + (size_t)b * (64 * 66 * 512);
    u16* hp16[2];
    int p2s[2];
#pragma unroll
    for (int mi = 0; mi < 2; mi++) {
        int p2 = 16 * (2 * mh + mi) + 4 * g4 + nq;
        p2s[mi] = p2;
        hp16[mi] = hh16 + (size_t)b * 262144 + p2 * 4032 + m15;
    }

    // ---- initial IV load (t=0) ----
    uint2 IV[2][4];
#pragma unroll
    for (int mi = 0; mi < 2; mi++) {
#pragma unroll
        for (int r = 0; r < 4; r++) {
            u32 o0 = min(max(offW[mi][r] - 512u, offLo[mi][r]), offHi[mi][r]);
            IV[mi][r] = *(const uint2*)(i2sB + o0);
        }
    }

    // ---- deferred-store carry state ----
    u16 hbKeep[2][4];
    u16* hpPrev[2];
    bool vstPrev[2];
#pragma unroll
    for (int mi = 0; mi < 2; mi++) {
        vstPrev[mi] = false;
        hpPrev[mi] = hp16[mi];
    }

    __syncthreads();

    for (int t = 0; t < NSTEP; t++) {
        // ---- deferred hh16 stores from step t-1 ----
#pragma unroll
        for (int mi = 0; mi < 2; mi++)
            if (vstPrev[mi]) {
#pragma unroll
                for (int nb = 0; nb < 4; nb++)
                    hpPrev[mi][nb * 16] = hbKeep[mi][nb];
            }

        // ---- c2c ONCE per step (row-interleaved tile serves both mi) ----
        f32x4 accC[4];
#pragma unroll
        for (int nb = 0; nb < 4; nb++) {
            accC[nb][0] = bcc[nb];
            accC[nb][1] = bcc[nb];
            accC[nb][2] = bcc[nb];
            accC[nb][3] = bcc[nb];
        }
        {
            bf16x8 Ac[4];
#pragma unroll
            for (int kt = 0; kt < 4; kt++)
                Ac[kt] = __builtin_bit_cast(bf16x8,
                                            *(const uint4*)(smB + aC[kt]));
#pragma unroll
            for (int nb = 0; nb < 4; nb++)
#pragma unroll
                for (int kt = 0; kt < 4; kt++)
                    accC[nb] = MFMA(Ac[kt], BC[nb][kt], accC[nb]);
        }

        // ---- per-mi: prefetch | acc-init+gates | LSTM+writes ----
#pragma unroll
        for (int mi = 0; mi < 2; mi++) {
            // prefetch IV for step t+1 (walked offsets, clamped)
            uint2 tn[4];
#pragma unroll
            for (int r = 0; r < 4; r++) {
                u32 oc = min(max(offW[mi][r], offLo[mi][r]), offHi[mi][r]);
                tn[r] = *(const uint2*)(i2sB + oc);
            }

            // gate MFMAs, acc initialized from current IV
            f32x4 accG[4];
#pragma unroll
            for (int r = 0; r < 4; r++) {
                accG[0][r] = lo2f(IV[mi][r].x);
                accG[1][r] = hi2f(IV[mi][r].x);
                accG[2][r] = lo2f(IV[mi][r].y);
                accG[3][r] = hi2f(IV[mi][r].y);
            }
            bf16x8 Ag[4];
#pragma unroll
            for (int kt = 0; kt < 4; kt++)
                Ag[kt] = __builtin_bit_cast(bf16x8,
                                            *(const uint4*)(smB + aG[mi][kt]));
#pragma unroll
            for (int nb = 0; nb < 4; nb++)
#pragma unroll
                for (int kt = 0; kt < 4; kt++)
                    accG[nb] = MFMA(Ag[kt], BW[nb][kt], accG[nb]);

            // LSTM update, rcp-fused; cc = accC[nb][mi] (static under unroll)
            int p2 = p2s[mi];
            bool vst = (u32)(t - p2) < 64u;
#pragma unroll
            for (int nb = 0; nb < 4; nb++) {
                float cc = accC[nb][mi];
                float pI = 1.f + __builtin_amdgcn_exp2f(accG[nb][0]);
                float pG = 1.f + __builtin_amdgcn_exp2f(accG[nb][1]);
                float pF = 1.f + __builtin_amdgcn_exp2f(accG[nb][2]);
                float pO = 1.f + __builtin_amdgcn_exp2f(accG[nb][3]);
                float u = pI * pG;
                float num = __builtin_fmaf(cc, u, pF);
                float c1 = num * __builtin_amdgcn_rcpf(pF * u);
                float E = __builtin_amdgcn_exp2f(c1 * T2L);
                float h1 =
                    (E - 1.f) * __builtin_amdgcn_rcpf((1.f + E) * pO);
                u32 hc = cvt_pk_bf16(h1, c1);  // lo=bf16(h1), hi=bf16(c1)
                *(u16*)(smB + wOff[mi][nb]) = (u16)hc;
                *(u16*)(smB + wOff[mi][nb] + 16384) = (u16)(hc >> 16);
                hbKeep[mi][nb] = (u16)hc;
            }
            vstPrev[mi] = vst;
            hpPrev[mi] = hp16[mi];
            hp16[mi] += 64;

            // rotate prefetched IV
#pragma unroll
            for (int r = 0; r < 4; r++) IV[mi][r] = tn[r];
        }

        __syncthreads();  // single barrier per step

        // ---- toggle parity; walk IV offsets ----
#pragma unroll
        for (int kt = 0; kt < 4; kt++) aC[kt] ^= 8192;
#pragma unroll
        for (int mi = 0; mi < 2; mi++) {
#pragma unroll
            for (int kt = 0; kt < 4; kt++) aG[mi][kt] ^= 8192;
#pragma unroll
            for (int nb = 0; nb < 4; nb++) {
                wOff[mi][nb] ^= 8192;
                offW[mi][nb] += 512;
            }
        }
    }

    // ---- epilogue: final deferred stores ----
#pragma unroll
    for (int mi = 0; mi < 2; mi++)
        if (vstPrev[mi]) {
#pragma unroll
            for (int nb = 0; nb < 4; nb++)
                hpPrev[mi][nb * 16] = hbKeep[mi][nb];
        }
}

// ---------------- K3: up-projection via MFMA ----------
__global__ __launch_bounds__(256, 4) void up_kernel(
    const u16* __restrict__ hh16, const u16* __restrict__ w_upB,
    const float* __restrict__ b_up, float* __restrict__ out) {
    const int bid = blockIdx.x;
    const int b = bid >> 6, r = bid & 63;
    const int lane = threadIdx.x & 63;
    const int wt = __builtin_amdgcn_readfirstlane(threadIdx.x >> 6);
    const int m15 = lane & 15, g4 = lane >> 4;

    const u16* hh_b = hh16 + (size_t)b * 262144;
    const int w = 16 * wt + m15;

    bf16x8 Bf[2];
#pragma unroll
    for (int kt = 0; kt < 2; kt++)
        Bf[kt] = __builtin_bit_cast(
            bf16x8,
            *(const uint4*)(hh_b + (r * 4096 + w * 64 + kt * 32 + g4 * 8)));

    // b_up via float4 (o2 = 16nt + 4g4 + rr, rr 0..3 contiguous)
    f32x4 bup[8];
#pragma unroll
    for (int nt = 0; nt < 8; nt++)
        bup[nt] =
            __builtin_bit_cast(f32x4, *(const float4*)(b_up + 16 * nt + 4 * g4));

    f32x4 acc[8] = {};
#pragma unroll
    for (int nt = 0; nt < 8; nt++) {
#pragma unroll
        for (int kt = 0; kt < 2; kt++) {
            bf16x8 Af = __builtin_bit_cast(
                bf16x8, *(const uint4*)(w_upB + ((16 * nt + m15) * 64 +
                                                 kt * 32 + g4 * 8)));
            acc[nt] = MFMA(Af, Bf[kt], acc[nt]);
        }
    }
    float* outb = out + (size_t)b * 524288;
#pragma unroll
    for (int nt = 0; nt < 8; nt++) {
#pragma unroll
        for (int rr = 0; rr < 4; rr++) {
            int o2 = 16 * nt + 4 * g4 + rr;
            outb[(size_t)o2 * 4096 + r * 64 + w] = acc[nt][rr] + bup[nt][rr];
        }
    }
}

extern "C" void kernel_launch(void* const* d_in, const int* in_sizes, int n_in,
                              void* d_out, int out_size, void* d_ws,
                              size_t ws_size, hipStream_t stream) {
    (void)in_sizes; (void)n_in; (void)out_size; (void)ws_size;
    const float* inputs = (const float*)d_in[0];
    const float* w_i2s = (const float*)d_in[1];
    const float* b_i2s = (const float*)d_in[2];
    const float* w_s2s = (const float*)d_in[3];
    const float* b_s2s = (const float*)d_in[4];
    const float* w_c2c = (const float*)d_in[5];
    const float* b_c2c = (const float*)d_in[6];
    const float* w_up = (const float*)d_in[7];
    const float* b_up = (const float*)d_in[8];
    float* out = (float*)d_out;
    char* ws = (char*)d_ws;

    // workspace layout (bytes):
    // [0, 69206016)             i2sP u16 (32*64*66*256, bias-padded slots)
    // [69206016, 85983232)      hh16 u16 (32*64*64*64)
    // [85983232, 86114304)      Wg fp32 (256*128, scaled -log2e)
    // [86114304, 86147072)      Wc fp32 (64*128)
    // [86147072, 86147584)      biasRow u16[256]
    // [86147584, 86163968)      w_upB u16 (128*64)
    u16* i2sP = (u16*)ws;
    u16* hh16 = (u16*)(ws + 69206016);
    float* Wg = (float*)(ws + 85983232);
    float* Wc = (float*)(ws + 86114304);
    u16* biasRow = (u16*)(ws + 86147072);
    u16* w_upB = (u16*)(ws + 86147584);

    hipLaunchKernelGGL(repack_w, dim3(193), dim3(256), 0, stream, w_s2s, w_c2c,
                       b_i2s, b_s2s, w_up, Wg, Wc, biasRow, w_upB);
    hipLaunchKernelGGL(i2s_kernel, dim3(2048), dim3(256), 0, stream, inputs,
                       w_i2s, b_i2s, b_s2s, (const u32*)biasRow, (u32*)i2sP);
    hipLaunchKernelGGL(scan_kernel, dim3(32), dim3(512), 0, stream, i2sP, Wg,
                       Wc, b_c2c, hh16);
    hipLaunchKernelGGL(up_kernel, dim3(2048), dim3(256), 0, stream, hh16,
                       w_upB, b_up, out);
}